// Round 2
// baseline (602.434 us; speedup 1.0000x reference)
//
#include <hip/hip_runtime.h>
#include <hip/hip_bf16.h>
#include <math.h>

#define IN_F   128
#define OUT_F  128
#define HEADS  8
#define HEAD_D 16
#define EDGE_F 64
#define BUCKET 64     // CSR bucket capacity per node

typedef __attribute__((ext_vector_type(8))) short bf16x8;
typedef __attribute__((ext_vector_type(4))) float f32x4;

// round-to-nearest-even fp32 -> bf16 bits
__device__ inline unsigned int f2bf(float f) {
    union { float f; unsigned int u; } c; c.f = f;
    unsigned int r = c.u + 0x7FFFu + ((c.u >> 16) & 1u);
    return r >> 16;
}

// kvp feature -> word permutation: word holds (k,v) packed; lane l ulong-loads
// words {2l, 2l+1} = features {h*16+r, h*16+r+8} with h=l>>3, r=l&7.
__device__ inline int wperm(int col) {
    return (col & 0x70) | ((col & 7) << 1) | ((col >> 3) & 1);
}

// ---- Prep: swizzle Wq/Wk/Wv/Wo into MFMA B-frag layout + zero deg ----
__global__ __launch_bounds__(256)
void prep_kernel(const float* __restrict__ Wq, const float* __restrict__ Wk,
                 const float* __restrict__ Wv, const float* __restrict__ Wo,
                 uint4* __restrict__ Wb, int* __restrict__ deg, int n_nodes) {
    int id = blockIdx.x * 256 + threadIdx.x;
    if (id < n_nodes) deg[id] = 0;
    if (id >= 8192) return;
    int lane = id & 63;
    int kb   = (id >> 6) & 3;
    int ct   = (id >> 8) & 7;
    int mat  = id >> 11;
    const float* W = (mat == 0) ? Wq : (mat == 1) ? Wk : (mat == 2) ? Wv : Wo;
    int n  = ct * 16 + (lane & 15);
    int k0 = kb * 32 + (lane >> 4) * 8;
    unsigned int t[8];
    #pragma unroll
    for (int j = 0; j < 8; ++j) t[j] = f2bf(W[(size_t)(k0 + j) * 128 + n]);
    uint4 val;
    val.x = t[0] | (t[1] << 16);
    val.y = t[2] | (t[3] << 16);
    val.z = t[4] | (t[5] << 16);
    val.w = t[6] | (t[7] << 16);
    Wb[id] = val;
}

// ---- Fused: QKV (node blocks) + edge-bias + CSR scatter (edge blocks) ----
__global__ __launch_bounds__(256)
void qkv_edges(const float* __restrict__ x, const bf16x8* __restrict__ WbV,
               const float* __restrict__ bq, const float* __restrict__ bk,
               const float* __restrict__ bv,
               float* __restrict__ q, unsigned int* __restrict__ kvp, int n_nodes,
               const float* __restrict__ ef, const float* __restrict__ We,
               const float* __restrict__ be, float* __restrict__ ebias,
               const int* __restrict__ ei, int* __restrict__ deg,
               int2* __restrict__ csr2, int n_edges, int node_blocks) {
    __shared__ float sWe[EDGE_F * HEADS];
    __shared__ float sbe[HEADS];
    const int tid = threadIdx.x;

    if ((int)blockIdx.x < node_blocks) {
        // ----------------- QKV via MFMA: 4 waves, 64 nodes/block -----------------
        const int wave = tid >> 6;
        const int lane = tid & 63;
        const int quad = lane >> 4;
        const int lcol = lane & 15;
        const int row0 = blockIdx.x * 64 + wave * 16;
        const int m    = row0 + lcol;                 // A-row this lane loads

        bf16x8 afrag[4];
        const bool mv = (m < n_nodes);
        const float* xr = x + (size_t)m * IN_F;
        #pragma unroll
        for (int kb = 0; kb < 4; ++kb) {
            float buf[8];
            if (mv) {
                float4 a = ((const float4*)(xr + kb * 32 + quad * 8))[0];
                float4 b = ((const float4*)(xr + kb * 32 + quad * 8 + 4))[0];
                buf[0]=a.x; buf[1]=a.y; buf[2]=a.z; buf[3]=a.w;
                buf[4]=b.x; buf[5]=b.y; buf[6]=b.z; buf[7]=b.w;
            } else {
                #pragma unroll
                for (int j = 0; j < 8; ++j) buf[j] = 0.f;
            }
            bf16x8 f;
            #pragma unroll
            for (int j = 0; j < 8; ++j) f[j] = (short)f2bf(buf[j]);
            afrag[kb] = f;
        }

        #pragma unroll
        for (int ct = 0; ct < 8; ++ct) {
            f32x4 aq = {0.f,0.f,0.f,0.f}, ak = {0.f,0.f,0.f,0.f}, av = {0.f,0.f,0.f,0.f};
            #pragma unroll
            for (int kb = 0; kb < 4; ++kb) {
                bf16x8 bq_ = WbV[((0 * 8 + ct) * 4 + kb) * 64 + lane];
                bf16x8 bk_ = WbV[((1 * 8 + ct) * 4 + kb) * 64 + lane];
                bf16x8 bv_ = WbV[((2 * 8 + ct) * 4 + kb) * 64 + lane];
                aq = __builtin_amdgcn_mfma_f32_16x16x32_bf16(afrag[kb], bq_, aq, 0, 0, 0);
                ak = __builtin_amdgcn_mfma_f32_16x16x32_bf16(afrag[kb], bk_, ak, 0, 0, 0);
                av = __builtin_amdgcn_mfma_f32_16x16x32_bf16(afrag[kb], bv_, av, 0, 0, 0);
            }
            const int col = ct * 16 + lcol;
            const int wcol = wperm(col);
            float bqc = bq[col], bkc = bk[col], bvc = bv[col];
            #pragma unroll
            for (int r = 0; r < 4; ++r) {
                int node = row0 + quad * 4 + r;       // C/D: row = quad*4+reg, col = lane&15
                if (node < n_nodes) {
                    q[(size_t)node * OUT_F + col]    = aq[r] + bqc;
                    kvp[(size_t)node * OUT_F + wcol] = f2bf(ak[r] + bkc) | (f2bf(av[r] + bvc) << 16);
                }
            }
        }
    } else {
        // ----------------- Edge bias + bucketed CSR scatter -----------------
        // Two-phase for memory-level parallelism: ALL loads issue first, the
        // atomic rides under the FMA reduction, dependent stores go last.
        for (int i = tid; i < EDGE_F * HEADS; i += 256) sWe[i] = We[i];
        if (tid < HEADS) sbe[tid] = be[tid];
        __syncthreads();

        const int e = (blockIdx.x - node_blocks) * 256 + tid;
        if (e >= n_edges) return;

        // phase 1: issue all 16 ef float4 loads into registers
        const float4* er = (const float4*)(ef + (size_t)e * EDGE_F);
        float4 buf[16];
        #pragma unroll
        for (int j4 = 0; j4 < 16; ++j4) buf[j4] = er[j4];

        // phase 2: indices + atomic (latency hidden under the FMA tree below)
        int s = ei[e];
        int t = ei[n_edges + e];
        int pos = atomicAdd(&deg[t], 1);

        // phase 3: FMA reduction — identical accumulation order to before
        float acc[HEADS];
        #pragma unroll
        for (int h = 0; h < HEADS; ++h) acc[h] = sbe[h];
        #pragma unroll
        for (int j4 = 0; j4 < 16; ++j4) {
            float ev[4] = {buf[j4].x, buf[j4].y, buf[j4].z, buf[j4].w};
            #pragma unroll
            for (int jj = 0; jj < 4; ++jj) {
                int j = j4 * 4 + jj;
                #pragma unroll
                for (int h = 0; h < HEADS; ++h)
                    acc[h] = fmaf(ev[jj], sWe[j * HEADS + h], acc[h]);
            }
        }

        // phase 4: dependent stores
        if (pos < BUCKET) csr2[((size_t)t << 6) + pos] = make_int2(s, e);
        float4* dst = (float4*)(ebias + (size_t)e * HEADS);
        dst[0] = make_float4(acc[0], acc[1], acc[2], acc[3]);
        dst[1] = make_float4(acc[4], acc[5], acc[6], acc[7]);
    }
}

// ---- Aggregation: 1 wave per target, 4 targets/block ----
// Two-stage prefetch pipeline: csr entries 8 slots ahead, kv/ebias 4 ahead
// (the csr->kvp chain is two dependent loads; one-stage prefetch only covers one).
// lane l owns features fa = (l>>3)*16 + (l&7) and fb = fa+8 via one ulong kvp load.
__global__ __launch_bounds__(256)
void agg_kernel(const int2* __restrict__ csr2, const int* __restrict__ deg,
                const float* __restrict__ q, const unsigned long long* __restrict__ kvpu,
                const float* __restrict__ ebias, unsigned short* __restrict__ aggn,
                int n_nodes) {
    const int tid  = threadIdx.x;
    const int wave = tid >> 6;
    const int lane = tid & 63;
    const int t    = blockIdx.x * 4 + wave;
    if (t >= n_nodes) return;

    const int h  = lane >> 3;
    const int r  = lane & 7;
    const int fa = h * 16 + r;          // fb = fa + 8

    const float qa = q[(size_t)t * OUT_F + fa];
    const float qb = q[(size_t)t * OUT_F + fa + 8];

    const int beg = t << 6;
    int cnt = deg[t]; if (cnt > BUCKET) cnt = BUCKET;
    const int end = beg + cnt;

    float acc_a = 0.f, acc_b = 0.f, den = 0.f;

    auto process = [&](unsigned long long kv, float eb) {
        unsigned int w0 = (unsigned int)kv;
        unsigned int w1 = (unsigned int)(kv >> 32);
        float ka = __uint_as_float(w0 << 16);
        float va = __uint_as_float(w0 & 0xFFFF0000u);
        float kb = __uint_as_float(w1 << 16);
        float vb = __uint_as_float(w1 & 0xFFFF0000u);
        // bit-identical tree: mul, in-lane add (= old mask-8 level), then 4,2,1
        float pa = __fmul_rn(qa, ka);
        float pb = __fmul_rn(qb, kb);
        float p  = __fadd_rn(pa, pb);
        p = __fadd_rn(p, __shfl_xor(p, 4, 8));
        p = __fadd_rn(p, __shfl_xor(p, 2, 8));
        p = __fadd_rn(p, __shfl_xor(p, 1, 8));
        float w = __expf(fmaf(p, 0.25f, eb));
        den += w;
        acc_a = fmaf(w, va, acc_a);
        acc_b = fmaf(w, vb, acc_b);
    };

    // stage-1 prefetch: csr entries for slots beg..beg+7
    int2 se[8];
    #pragma unroll
    for (int j = 0; j < 8; ++j)
        se[j] = (beg + j < end) ? csr2[beg + j] : make_int2(0, 0);

    // stage-2 prefetch: kv/ebias for slots beg..beg+3
    unsigned long long kv[4]; float eb[4];
    #pragma unroll
    for (int j = 0; j < 4; ++j) {
        kv[j] = 0; eb[j] = 0.f;
        if (beg + j < end) {
            kv[j] = kvpu[(size_t)se[j].x * 64 + lane];
            eb[j] = ebias[(size_t)se[j].y * HEADS + h];
        }
    }

    int i = beg;
    while (i + 3 < end) {
        // prefetch csr for slots i+8..i+11
        int2 nse[4];
        #pragma unroll
        for (int j = 0; j < 4; ++j)
            nse[j] = (i + 8 + j < end) ? csr2[i + 8 + j] : make_int2(0, 0);
        // prefetch kv/ebias for slots i+4..i+7 (csr already resident in se[4..7])
        unsigned long long nkv[4]; float neb[4];
        #pragma unroll
        for (int j = 0; j < 4; ++j) {
            nkv[j] = 0; neb[j] = 0.f;
            if (i + 4 + j < end) {
                nkv[j] = kvpu[(size_t)se[4 + j].x * 64 + lane];
                neb[j] = ebias[(size_t)se[4 + j].y * HEADS + h];
            }
        }
        process(kv[0], eb[0]);
        process(kv[1], eb[1]);
        process(kv[2], eb[2]);
        process(kv[3], eb[3]);
        #pragma unroll
        for (int j = 0; j < 4; ++j) { se[j] = se[4 + j]; se[4 + j] = nse[j]; }
        #pragma unroll
        for (int j = 0; j < 4; ++j) { kv[j] = nkv[j]; eb[j] = neb[j]; }
        i += 4;
    }
    if (i < end)     process(kv[0], eb[0]);
    if (i + 1 < end) process(kv[1], eb[1]);
    if (i + 2 < end) process(kv[2], eb[2]);

    float d = den + 1e-10f;
    aggn[(size_t)t * OUT_F + fa]     = (unsigned short)f2bf(acc_a / d);
    aggn[(size_t)t * OUT_F + fa + 8] = (unsigned short)f2bf(acc_b / d);
}

// ---- Output projection via MFMA: aggn (bf16) @ Wo + bo ----
__global__ __launch_bounds__(256)
void out_mfma(const unsigned short* __restrict__ aggn, const bf16x8* __restrict__ WbV,
              const float* __restrict__ bo, float* __restrict__ out, int n_nodes) {
    const int tid  = threadIdx.x;
    const int wave = tid >> 6;
    const int lane = tid & 63;
    const int quad = lane >> 4;
    const int lcol = lane & 15;
    const int row0 = blockIdx.x * 64 + wave * 16;
    const int m    = row0 + lcol;

    bf16x8 afrag[4];
    const bool mv = (m < n_nodes);
    const bf16x8* ar = (const bf16x8*)(aggn + (size_t)m * OUT_F);
    #pragma unroll
    for (int kb = 0; kb < 4; ++kb) {
        if (mv) afrag[kb] = ar[kb * 4 + quad];
        else {
            bf16x8 z;
            #pragma unroll
            for (int j = 0; j < 8; ++j) z[j] = 0;
            afrag[kb] = z;
        }
    }

    #pragma unroll
    for (int ct = 0; ct < 8; ++ct) {
        f32x4 acc = {0.f, 0.f, 0.f, 0.f};
        #pragma unroll
        for (int kb = 0; kb < 4; ++kb) {
            bf16x8 b = WbV[((3 * 8 + ct) * 4 + kb) * 64 + lane];
            acc = __builtin_amdgcn_mfma_f32_16x16x32_bf16(afrag[kb], b, acc, 0, 0, 0);
        }
        const int col = ct * 16 + lcol;
        float boc = bo[col];
        #pragma unroll
        for (int r = 0; r < 4; ++r) {
            int node = row0 + quad * 4 + r;
            if (node < n_nodes) out[(size_t)node * OUT_F + col] = acc[r] + boc;
        }
    }
}

extern "C" void kernel_launch(void* const* d_in, const int* in_sizes, int n_in,
                              void* d_out, int out_size, void* d_ws, size_t ws_size,
                              hipStream_t stream) {
    const float* x  = (const float*)d_in[0];
    const int*   ei = (const int*)  d_in[1];
    const float* ef = (const float*)d_in[2];
    const float* Wq = (const float*)d_in[3];
    const float* bq = (const float*)d_in[4];
    const float* Wk = (const float*)d_in[5];
    const float* bk = (const float*)d_in[6];
    const float* Wv = (const float*)d_in[7];
    const float* bv = (const float*)d_in[8];
    const float* We = (const float*)d_in[9];
    const float* be = (const float*)d_in[10];
    const float* Wo = (const float*)d_in[11];
    const float* bo = (const float*)d_in[12];
    float* out = (float*)d_out;

    const int n_nodes = in_sizes[0] / IN_F;
    const int n_edges = in_sizes[1] / 2;

    char* w = (char*)d_ws;
    float*          q     = (float*)w;          w += (size_t)n_nodes * OUT_F * 4;
    unsigned int*   kvp   = (unsigned int*)w;   w += (size_t)n_nodes * OUT_F * 4;
    float*          ebias = (float*)w;          w += (size_t)n_edges * HEADS * 4;
    unsigned short* aggn  = (unsigned short*)w; w += (size_t)n_nodes * OUT_F * 2;
    uint4*          Wb    = (uint4*)w;          w += (size_t)8192 * 16;
    int*            deg   = (int*)w;            w += (size_t)n_nodes * 4;
    int2*           csr2  = (int2*)w;           // [N*64] (src, edge)

    // 1. weight swizzle + deg zeroing
    {
        int threads_needed = (n_nodes > 8192) ? n_nodes : 8192;
        prep_kernel<<<(threads_needed + 255) / 256, 256, 0, stream>>>(
            Wq, Wk, Wv, Wo, Wb, deg, n_nodes);
    }

    // 2. fused QKV + edge-bias + CSR scatter
    {
        int node_blocks = (n_nodes + 63) / 64;
        int edge_blocks = (n_edges + 255) / 256;
        qkv_edges<<<node_blocks + edge_blocks, 256, 0, stream>>>(
            x, (const bf16x8*)Wb, bq, bk, bv, q, kvp, n_nodes,
            ef, We, be, ebias, ei, deg, csr2, n_edges, node_blocks);
    }

    // 3. aggregation (1 wave per target, 4 targets per block)
    agg_kernel<<<(n_nodes + 3) / 4, 256, 0, stream>>>(
        csr2, deg, q, (const unsigned long long*)kvp, ebias, aggn, n_nodes);

    // 4. output projection
    out_mfma<<<(n_nodes + 63) / 64, 256, 0, stream>>>(
        aggn, (const bf16x8*)Wb, bo, out, n_nodes);
}

// Round 3
// 563.488 us; speedup vs baseline: 1.0691x; 1.0691x over previous
//
#include <hip/hip_runtime.h>
#include <hip/hip_bf16.h>
#include <math.h>

#define IN_F   128
#define OUT_F  128
#define HEADS  8
#define HEAD_D 16
#define EDGE_F 64
#define BUCKET 64     // CSR bucket capacity per node

typedef __attribute__((ext_vector_type(8))) short bf16x8;
typedef __attribute__((ext_vector_type(4))) float f32x4;

// round-to-nearest-even fp32 -> bf16 bits
__device__ inline unsigned int f2bf(float f) {
    union { float f; unsigned int u; } c; c.f = f;
    unsigned int r = c.u + 0x7FFFu + ((c.u >> 16) & 1u);
    return r >> 16;
}

// kvp feature -> word permutation: word holds (k,v) packed; lane l ulong-loads
// words {2l, 2l+1} = features {h*16+r, h*16+r+8} with h=l>>3, r=l&7.
__device__ inline int wperm(int col) {
    return (col & 0x70) | ((col & 7) << 1) | ((col >> 3) & 1);
}

// ---- Prep: swizzle Wq/Wk/Wv/Wo into MFMA B-frag layout + zero deg ----
__global__ __launch_bounds__(256)
void prep_kernel(const float* __restrict__ Wq, const float* __restrict__ Wk,
                 const float* __restrict__ Wv, const float* __restrict__ Wo,
                 uint4* __restrict__ Wb, int* __restrict__ deg, int n_nodes) {
    int id = blockIdx.x * 256 + threadIdx.x;
    if (id < n_nodes) deg[id] = 0;
    if (id >= 8192) return;
    int lane = id & 63;
    int kb   = (id >> 6) & 3;
    int ct   = (id >> 8) & 7;
    int mat  = id >> 11;
    const float* W = (mat == 0) ? Wq : (mat == 1) ? Wk : (mat == 2) ? Wv : Wo;
    int n  = ct * 16 + (lane & 15);
    int k0 = kb * 32 + (lane >> 4) * 8;
    unsigned int t[8];
    #pragma unroll
    for (int j = 0; j < 8; ++j) t[j] = f2bf(W[(size_t)(k0 + j) * 128 + n]);
    uint4 val;
    val.x = t[0] | (t[1] << 16);
    val.y = t[2] | (t[3] << 16);
    val.z = t[4] | (t[5] << 16);
    val.w = t[6] | (t[7] << 16);
    Wb[id] = val;
}

// ---- Fused: QKV (node blocks) + edge-bias/scatter (edge blocks) ----
// Edge blocks: 1 wave = 8 edges; lane l = (edge l>>3, chunk l&7).
// Each lane loads 8 ef floats (2 float4), 64 FMAs vs LDS We (pad-9 layout),
// 3-stage shfl_xor tree over the 8-lane group, bucket-ordered bias store.
__global__ __launch_bounds__(256)
void qkv_edges(const float* __restrict__ x, const bf16x8* __restrict__ WbV,
               const float* __restrict__ bq, const float* __restrict__ bk,
               const float* __restrict__ bv,
               float* __restrict__ q, unsigned int* __restrict__ kvp, int n_nodes,
               const float* __restrict__ ef, const float* __restrict__ We,
               const float* __restrict__ be, float* __restrict__ ebias_csr,
               const int* __restrict__ ei, int* __restrict__ deg,
               int* __restrict__ csr_src, int n_edges, int node_blocks) {
    __shared__ float sWe[EDGE_F * 9];   // pad 8->9: lanes c=0..7 hit 4 banks x 2 (free)
    __shared__ float sbe[HEADS];
    const int tid = threadIdx.x;

    if ((int)blockIdx.x < node_blocks) {
        // ----------------- QKV via MFMA: 4 waves, 64 nodes/block -----------------
        const int wave = tid >> 6;
        const int lane = tid & 63;
        const int quad = lane >> 4;
        const int lcol = lane & 15;
        const int row0 = blockIdx.x * 64 + wave * 16;
        const int m    = row0 + lcol;                 // A-row this lane loads

        bf16x8 afrag[4];
        const bool mv = (m < n_nodes);
        const float* xr = x + (size_t)m * IN_F;
        #pragma unroll
        for (int kb = 0; kb < 4; ++kb) {
            float buf[8];
            if (mv) {
                float4 a = ((const float4*)(xr + kb * 32 + quad * 8))[0];
                float4 b = ((const float4*)(xr + kb * 32 + quad * 8 + 4))[0];
                buf[0]=a.x; buf[1]=a.y; buf[2]=a.z; buf[3]=a.w;
                buf[4]=b.x; buf[5]=b.y; buf[6]=b.z; buf[7]=b.w;
            } else {
                #pragma unroll
                for (int j = 0; j < 8; ++j) buf[j] = 0.f;
            }
            bf16x8 f;
            #pragma unroll
            for (int j = 0; j < 8; ++j) f[j] = (short)f2bf(buf[j]);
            afrag[kb] = f;
        }

        #pragma unroll
        for (int ct = 0; ct < 8; ++ct) {
            f32x4 aq = {0.f,0.f,0.f,0.f}, ak = {0.f,0.f,0.f,0.f}, av = {0.f,0.f,0.f,0.f};
            #pragma unroll
            for (int kb = 0; kb < 4; ++kb) {
                bf16x8 bq_ = WbV[((0 * 8 + ct) * 4 + kb) * 64 + lane];
                bf16x8 bk_ = WbV[((1 * 8 + ct) * 4 + kb) * 64 + lane];
                bf16x8 bv_ = WbV[((2 * 8 + ct) * 4 + kb) * 64 + lane];
                aq = __builtin_amdgcn_mfma_f32_16x16x32_bf16(afrag[kb], bq_, aq, 0, 0, 0);
                ak = __builtin_amdgcn_mfma_f32_16x16x32_bf16(afrag[kb], bk_, ak, 0, 0, 0);
                av = __builtin_amdgcn_mfma_f32_16x16x32_bf16(afrag[kb], bv_, av, 0, 0, 0);
            }
            const int col = ct * 16 + lcol;
            const int wcol = wperm(col);
            float bqc = bq[col], bkc = bk[col], bvc = bv[col];
            #pragma unroll
            for (int r = 0; r < 4; ++r) {
                int node = row0 + quad * 4 + r;       // C/D: row = quad*4+reg, col = lane&15
                if (node < n_nodes) {
                    q[(size_t)node * OUT_F + col]    = aq[r] + bqc;
                    kvp[(size_t)node * OUT_F + wcol] = f2bf(ak[r] + bkc) | (f2bf(av[r] + bvc) << 16);
                }
            }
        }
    } else {
        // ----------------- Edge bias + bucketed CSR scatter (8 edges/wave) -----------------
        #pragma unroll
        for (int i = tid; i < EDGE_F * HEADS; i += 256)
            sWe[(i >> 3) * 9 + (i & 7)] = We[i];
        if (tid < HEADS) sbe[tid] = be[tid];
        __syncthreads();

        const int wave = tid >> 6;
        const int lane = tid & 63;
        const int g    = lane >> 3;     // edge within wave
        const int c    = lane & 7;      // 8-float chunk of the ef row
        const int e    = (blockIdx.x - node_blocks) * 32 + wave * 8 + g;
        const bool ok  = (e < n_edges);

        // 2 float4 loads per lane; wave covers 8 full ef rows (2 KB contiguous)
        float4 a = make_float4(0.f,0.f,0.f,0.f), b = a;
        if (ok) {
            const float4* er = (const float4*)(ef + (size_t)e * EDGE_F + c * 8);
            a = er[0]; b = er[1];
        }

        // one lane per edge: indices + atomic + src store
        int t_ = 0, pos = BUCKET;
        if (ok && c == 0) {
            int s_ = ei[e];
            t_ = ei[n_edges + e];
            pos = atomicAdd(&deg[t_], 1);
            if (pos < BUCKET) csr_src[((size_t)t_ << 6) + pos] = s_;
        }

        // partial MLP: 8 ef values x 8 heads
        float acc[HEADS];
        #pragma unroll
        for (int h = 0; h < HEADS; ++h) acc[h] = 0.f;
        float evv[8] = {a.x, a.y, a.z, a.w, b.x, b.y, b.z, b.w};
        #pragma unroll
        for (int jj = 0; jj < 8; ++jj) {
            #pragma unroll
            for (int h = 0; h < HEADS; ++h)
                acc[h] = fmaf(evv[jj], sWe[(c * 8 + jj) * 9 + h], acc[h]);
        }
        // reduce across the 8-lane group
        #pragma unroll
        for (int m = 1; m < 8; m <<= 1) {
            #pragma unroll
            for (int h = 0; h < HEADS; ++h)
                acc[h] += __shfl_xor(acc[h], m, 8);
        }
        // broadcast (t,pos) from the group's lane 0; each lane stores one head
        int slot = __shfl(pos, lane & 56);
        int tb   = __shfl(t_,  lane & 56);
        if (ok && slot < BUCKET)
            ebias_csr[(((size_t)tb << 6) + slot) * HEADS + c] = acc[c] + sbe[c];
    }
}

// ---- Aggregation: 1 wave per target, 4 targets/block ----
// csr row (64 src ints) loaded once, coalesced; distributed via shfl -> kv gather
// addresses available immediately; 8-deep kv + eb pipeline. eb reads are linear.
// lane l owns features fa=(l>>3)*16+(l&7), fb=fa+8 via one ulong kvp load.
__global__ __launch_bounds__(256)
void agg_kernel(const int* __restrict__ csr_src, const int* __restrict__ deg,
                const float* __restrict__ q, const unsigned long long* __restrict__ kvpu,
                const float* __restrict__ ebias_csr, unsigned short* __restrict__ aggn,
                int n_nodes) {
    const int tid  = threadIdx.x;
    const int wave = tid >> 6;
    const int lane = tid & 63;
    const int t    = blockIdx.x * 4 + wave;
    if (t >= n_nodes) return;

    const int h  = lane >> 3;
    const int r  = lane & 7;
    const int fa = h * 16 + r;          // fb = fa + 8

    const float qa = q[(size_t)t * OUT_F + fa];
    const float qb = q[(size_t)t * OUT_F + fa + 8];

    const int beg = t << 6;
    int cnt = deg[t]; if (cnt > BUCKET) cnt = BUCKET;

    // whole csr row in one coalesced load; entries >= cnt never consumed
    const int csrv = csr_src[beg + lane];

    float acc_a = 0.f, acc_b = 0.f, den = 0.f;

    auto process = [&](unsigned long long kv, float eb) {
        unsigned int w0 = (unsigned int)kv;
        unsigned int w1 = (unsigned int)(kv >> 32);
        float ka = __uint_as_float(w0 << 16);
        float va = __uint_as_float(w0 & 0xFFFF0000u);
        float kb = __uint_as_float(w1 << 16);
        float vb = __uint_as_float(w1 & 0xFFFF0000u);
        // bit-identical tree: mul, in-lane add (= old mask-8 level), then 4,2,1
        float pa = __fmul_rn(qa, ka);
        float pb = __fmul_rn(qb, kb);
        float p  = __fadd_rn(pa, pb);
        p = __fadd_rn(p, __shfl_xor(p, 4, 8));
        p = __fadd_rn(p, __shfl_xor(p, 2, 8));
        p = __fadd_rn(p, __shfl_xor(p, 1, 8));
        float w = __expf(fmaf(p, 0.25f, eb));
        den += w;
        acc_a = fmaf(w, va, acc_a);
        acc_b = fmaf(w, vb, acc_b);
    };

    unsigned long long kv[8]; float eb[8];
    #pragma unroll
    for (int j = 0; j < 8; ++j) {
        kv[j] = 0; eb[j] = 0.f;
        if (j < cnt) {
            int src = __shfl(csrv, j);
            kv[j] = kvpu[(size_t)src * 64 + lane];
            eb[j] = ebias_csr[(size_t)(beg + j) * HEADS + h];
        }
    }

    int i = 0;
    while (i + 8 <= cnt) {
        unsigned long long nkv[8]; float neb[8];
        #pragma unroll
        for (int j = 0; j < 8; ++j) {
            nkv[j] = 0; neb[j] = 0.f;
            if (i + 8 + j < cnt) {
                int src = __shfl(csrv, i + 8 + j);
                nkv[j] = kvpu[(size_t)src * 64 + lane];
                neb[j] = ebias_csr[(size_t)(beg + i + 8 + j) * HEADS + h];
            }
        }
        #pragma unroll
        for (int j = 0; j < 8; ++j) process(kv[j], eb[j]);
        #pragma unroll
        for (int j = 0; j < 8; ++j) { kv[j] = nkv[j]; eb[j] = neb[j]; }
        i += 8;
    }
    #pragma unroll
    for (int j = 0; j < 8; ++j)
        if (i + j < cnt) process(kv[j], eb[j]);

    float d = den + 1e-10f;
    aggn[(size_t)t * OUT_F + fa]     = (unsigned short)f2bf(acc_a / d);
    aggn[(size_t)t * OUT_F + fa + 8] = (unsigned short)f2bf(acc_b / d);
}

// ---- Output projection via MFMA: aggn (bf16) @ Wo + bo ----
__global__ __launch_bounds__(256)
void out_mfma(const unsigned short* __restrict__ aggn, const bf16x8* __restrict__ WbV,
              const float* __restrict__ bo, float* __restrict__ out, int n_nodes) {
    const int tid  = threadIdx.x;
    const int wave = tid >> 6;
    const int lane = tid & 63;
    const int quad = lane >> 4;
    const int lcol = lane & 15;
    const int row0 = blockIdx.x * 64 + wave * 16;
    const int m    = row0 + lcol;

    bf16x8 afrag[4];
    const bool mv = (m < n_nodes);
    const bf16x8* ar = (const bf16x8*)(aggn + (size_t)m * OUT_F);
    #pragma unroll
    for (int kb = 0; kb < 4; ++kb) {
        if (mv) afrag[kb] = ar[kb * 4 + quad];
        else {
            bf16x8 z;
            #pragma unroll
            for (int j = 0; j < 8; ++j) z[j] = 0;
            afrag[kb] = z;
        }
    }

    #pragma unroll
    for (int ct = 0; ct < 8; ++ct) {
        f32x4 acc = {0.f, 0.f, 0.f, 0.f};
        #pragma unroll
        for (int kb = 0; kb < 4; ++kb) {
            bf16x8 b = WbV[((3 * 8 + ct) * 4 + kb) * 64 + lane];
            acc = __builtin_amdgcn_mfma_f32_16x16x32_bf16(afrag[kb], b, acc, 0, 0, 0);
        }
        const int col = ct * 16 + lcol;
        float boc = bo[col];
        #pragma unroll
        for (int r = 0; r < 4; ++r) {
            int node = row0 + quad * 4 + r;
            if (node < n_nodes) out[(size_t)node * OUT_F + col] = acc[r] + boc;
        }
    }
}

extern "C" void kernel_launch(void* const* d_in, const int* in_sizes, int n_in,
                              void* d_out, int out_size, void* d_ws, size_t ws_size,
                              hipStream_t stream) {
    const float* x  = (const float*)d_in[0];
    const int*   ei = (const int*)  d_in[1];
    const float* ef = (const float*)d_in[2];
    const float* Wq = (const float*)d_in[3];
    const float* bq = (const float*)d_in[4];
    const float* Wk = (const float*)d_in[5];
    const float* bk = (const float*)d_in[6];
    const float* Wv = (const float*)d_in[7];
    const float* bv = (const float*)d_in[8];
    const float* We = (const float*)d_in[9];
    const float* be = (const float*)d_in[10];
    const float* Wo = (const float*)d_in[11];
    const float* bo = (const float*)d_in[12];
    float* out = (float*)d_out;

    const int n_nodes = in_sizes[0] / IN_F;
    const int n_edges = in_sizes[1] / 2;

    char* w = (char*)d_ws;
    float*          q       = (float*)w;          w += (size_t)n_nodes * OUT_F * 4;
    unsigned int*   kvp     = (unsigned int*)w;   w += (size_t)n_nodes * OUT_F * 4;
    unsigned short* aggn    = (unsigned short*)w; w += (size_t)n_nodes * OUT_F * 2;
    uint4*          Wb      = (uint4*)w;          w += (size_t)8192 * 16;
    int*            deg     = (int*)w;            w += (size_t)n_nodes * 4;
    int*            csr_src = (int*)w;            w += (size_t)n_nodes * BUCKET * 4;
    float*          ebias_csr = (float*)w;        // [N*64*8] bucket-ordered bias

    // 1. weight swizzle + deg zeroing
    {
        int threads_needed = (n_nodes > 8192) ? n_nodes : 8192;
        prep_kernel<<<(threads_needed + 255) / 256, 256, 0, stream>>>(
            Wq, Wk, Wv, Wo, Wb, deg, n_nodes);
    }

    // 2. fused QKV + edge-bias + CSR scatter (8 edges per wave)
    {
        int node_blocks = (n_nodes + 63) / 64;
        int edge_blocks = (n_edges + 31) / 32;
        qkv_edges<<<node_blocks + edge_blocks, 256, 0, stream>>>(
            x, (const bf16x8*)Wb, bq, bk, bv, q, kvp, n_nodes,
            ef, We, be, ebias_csr, ei, deg, csr_src, n_edges, node_blocks);
    }

    // 3. aggregation (1 wave per target, 4 targets per block)
    agg_kernel<<<(n_nodes + 3) / 4, 256, 0, stream>>>(
        csr_src, deg, q, (const unsigned long long*)kvp, ebias_csr, aggn, n_nodes);

    // 4. output projection
    out_mfma<<<(n_nodes + 63) / 64, 256, 0, stream>>>(
        aggn, (const bf16x8*)Wb, bo, out, n_nodes);
}

// Round 4
// 519.178 us; speedup vs baseline: 1.1604x; 1.0853x over previous
//
#include <hip/hip_runtime.h>
#include <hip/hip_bf16.h>
#include <math.h>

#define IN_F   128
#define OUT_F  128
#define HEADS  8
#define HEAD_D 16
#define EDGE_F 64
#define BUCKET 64     // CSR bucket capacity per node

typedef __attribute__((ext_vector_type(8))) short bf16x8;
typedef __attribute__((ext_vector_type(4))) float f32x4;

// round-to-nearest-even fp32 -> bf16 bits
__device__ inline unsigned int f2bf(float f) {
    union { float f; unsigned int u; } c; c.f = f;
    unsigned int r = c.u + 0x7FFFu + ((c.u >> 16) & 1u);
    return r >> 16;
}

// kvp feature -> word permutation: word holds (k,v) packed; lane l ulong-loads
// words {2l, 2l+1} = features {h*16+r, h*16+r+8} with h=l>>3, r=l&7.
__device__ inline int wperm(int col) {
    return (col & 0x70) | ((col & 7) << 1) | ((col >> 3) & 1);
}

// ---- Prep: swizzle Wq/Wk/Wv/Wo into MFMA B-frag layout + zero deg ----
__global__ __launch_bounds__(256)
void prep_kernel(const float* __restrict__ Wq, const float* __restrict__ Wk,
                 const float* __restrict__ Wv, const float* __restrict__ Wo,
                 uint4* __restrict__ Wb, int* __restrict__ deg, int n_nodes) {
    int id = blockIdx.x * 256 + threadIdx.x;
    if (id < n_nodes) deg[id] = 0;
    if (id >= 8192) return;
    int lane = id & 63;
    int kb   = (id >> 6) & 3;
    int ct   = (id >> 8) & 7;
    int mat  = id >> 11;
    const float* W = (mat == 0) ? Wq : (mat == 1) ? Wk : (mat == 2) ? Wv : Wo;
    int n  = ct * 16 + (lane & 15);
    int k0 = kb * 32 + (lane >> 4) * 8;
    unsigned int t[8];
    #pragma unroll
    for (int j = 0; j < 8; ++j) t[j] = f2bf(W[(size_t)(k0 + j) * 128 + n]);
    uint4 val;
    val.x = t[0] | (t[1] << 16);
    val.y = t[2] | (t[3] << 16);
    val.z = t[4] | (t[5] << 16);
    val.w = t[6] | (t[7] << 16);
    Wb[id] = val;
}

// ---- Fused: QKV (node blocks) + edge-bias/scatter (edge blocks) ----
// Edge blocks: 1 wave = 16 edges; lane l = (edge l>>2, quarter l&3).
// Lane loads 16 ef floats (4 float4), 128 FMAs vs LDS We, 2-stage shfl_xor
// butterfly over the 4-lane group, edge-ordered COALESCED bias store.
__global__ __launch_bounds__(256)
void qkv_edges(const float* __restrict__ x, const bf16x8* __restrict__ WbV,
               const float* __restrict__ bq, const float* __restrict__ bk,
               const float* __restrict__ bv,
               float* __restrict__ q, unsigned int* __restrict__ kvp, int n_nodes,
               const float* __restrict__ ef, const float* __restrict__ We,
               const float* __restrict__ be, float* __restrict__ ebias,
               const int* __restrict__ ei, int* __restrict__ deg,
               int2* __restrict__ csr2, int n_edges, int node_blocks) {
    __shared__ float sWe[EDGE_F * 9];   // pad 8->9
    __shared__ float sbe[HEADS];
    const int tid = threadIdx.x;

    if ((int)blockIdx.x < node_blocks) {
        // ----------------- QKV via MFMA: 4 waves, 64 nodes/block -----------------
        const int wave = tid >> 6;
        const int lane = tid & 63;
        const int quad = lane >> 4;
        const int lcol = lane & 15;
        const int row0 = blockIdx.x * 64 + wave * 16;
        const int m    = row0 + lcol;                 // A-row this lane loads

        bf16x8 afrag[4];
        const bool mv = (m < n_nodes);
        const float* xr = x + (size_t)m * IN_F;
        #pragma unroll
        for (int kb = 0; kb < 4; ++kb) {
            float buf[8];
            if (mv) {
                float4 a = ((const float4*)(xr + kb * 32 + quad * 8))[0];
                float4 b = ((const float4*)(xr + kb * 32 + quad * 8 + 4))[0];
                buf[0]=a.x; buf[1]=a.y; buf[2]=a.z; buf[3]=a.w;
                buf[4]=b.x; buf[5]=b.y; buf[6]=b.z; buf[7]=b.w;
            } else {
                #pragma unroll
                for (int j = 0; j < 8; ++j) buf[j] = 0.f;
            }
            bf16x8 f;
            #pragma unroll
            for (int j = 0; j < 8; ++j) f[j] = (short)f2bf(buf[j]);
            afrag[kb] = f;
        }

        #pragma unroll
        for (int ct = 0; ct < 8; ++ct) {
            f32x4 aq = {0.f,0.f,0.f,0.f}, ak = {0.f,0.f,0.f,0.f}, av = {0.f,0.f,0.f,0.f};
            #pragma unroll
            for (int kb = 0; kb < 4; ++kb) {
                bf16x8 bq_ = WbV[((0 * 8 + ct) * 4 + kb) * 64 + lane];
                bf16x8 bk_ = WbV[((1 * 8 + ct) * 4 + kb) * 64 + lane];
                bf16x8 bv_ = WbV[((2 * 8 + ct) * 4 + kb) * 64 + lane];
                aq = __builtin_amdgcn_mfma_f32_16x16x32_bf16(afrag[kb], bq_, aq, 0, 0, 0);
                ak = __builtin_amdgcn_mfma_f32_16x16x32_bf16(afrag[kb], bk_, ak, 0, 0, 0);
                av = __builtin_amdgcn_mfma_f32_16x16x32_bf16(afrag[kb], bv_, av, 0, 0, 0);
            }
            const int col = ct * 16 + lcol;
            const int wcol = wperm(col);
            float bqc = bq[col], bkc = bk[col], bvc = bv[col];
            #pragma unroll
            for (int r = 0; r < 4; ++r) {
                int node = row0 + quad * 4 + r;       // C/D: row = quad*4+reg, col = lane&15
                if (node < n_nodes) {
                    q[(size_t)node * OUT_F + col]    = aq[r] + bqc;
                    kvp[(size_t)node * OUT_F + wcol] = f2bf(ak[r] + bkc) | (f2bf(av[r] + bvc) << 16);
                }
            }
        }
    } else {
        // --------- Edge bias + bucketed CSR scatter (16 edges/wave, 4 lanes/edge) ---------
        #pragma unroll
        for (int i = tid; i < EDGE_F * HEADS; i += 256)
            sWe[(i >> 3) * 9 + (i & 7)] = We[i];
        if (tid < HEADS) sbe[tid] = be[tid];
        __syncthreads();

        const int wave = tid >> 6;
        const int lane = tid & 63;
        const int g    = lane >> 2;     // edge within wave (0..15)
        const int c    = lane & 3;      // 16-float quarter of the ef row
        const int e    = (blockIdx.x - node_blocks) * 64 + wave * 16 + g;
        const bool ok  = (e < n_edges);

        // 4 float4 loads per lane; wave covers 16 full ef rows (4 KB contiguous)
        float4 a0, a1, a2, a3;
        a0 = a1 = a2 = a3 = make_float4(0.f, 0.f, 0.f, 0.f);
        if (ok) {
            const float4* er = (const float4*)(ef + (size_t)e * EDGE_F + c * 16);
            a0 = er[0]; a1 = er[1]; a2 = er[2]; a3 = er[3];
        }

        // one lane per edge: indices + atomic + csr store (hidden under FMA tree)
        if (ok && c == 0) {
            int s_ = ei[e];
            int t_ = ei[n_edges + e];
            int pos = atomicAdd(&deg[t_], 1);
            if (pos < BUCKET) csr2[((size_t)t_ << 6) + pos] = make_int2(s_, e);
        }

        // partial MLP: 16 ef values x 8 heads
        float acc[HEADS];
        #pragma unroll
        for (int h = 0; h < HEADS; ++h) acc[h] = 0.f;
        float evv[16] = {a0.x, a0.y, a0.z, a0.w, a1.x, a1.y, a1.z, a1.w,
                         a2.x, a2.y, a2.z, a2.w, a3.x, a3.y, a3.z, a3.w};
        #pragma unroll
        for (int jj = 0; jj < 16; ++jj) {
            #pragma unroll
            for (int h = 0; h < HEADS; ++h)
                acc[h] = fmaf(evv[jj], sWe[(c * 16 + jj) * 9 + h], acc[h]);
        }
        // butterfly over the 4-lane group
        #pragma unroll
        for (int m = 1; m < 4; m <<= 1) {
            #pragma unroll
            for (int h = 0; h < HEADS; ++h)
                acc[h] += __shfl_xor(acc[h], m, 4);
        }
        // edge-ordered coalesced store: lane c writes heads {2c, 2c+1}
        if (ok) {
            float2 st = make_float2(acc[2 * c]     + sbe[2 * c],
                                    acc[2 * c + 1] + sbe[2 * c + 1]);
            ((float2*)(ebias + (size_t)e * HEADS))[c] = st;
        }
    }
}

// ---- Aggregation: 1 wave per target, 4 targets/block ----
// csr row (64 int2) loaded once, coalesced; src/edge distributed via shfl ->
// gather addresses available instantly; 8-deep kv + eb prefetch pipeline.
// lane l owns features fa=(l>>3)*16+(l&7), fb=fa+8 via one ulong kvp load.
__global__ __launch_bounds__(256)
void agg_kernel(const int2* __restrict__ csr2, const int* __restrict__ deg,
                const float* __restrict__ q, const unsigned long long* __restrict__ kvpu,
                const float* __restrict__ ebias, unsigned short* __restrict__ aggn,
                int n_nodes) {
    const int tid  = threadIdx.x;
    const int wave = tid >> 6;
    const int lane = tid & 63;
    const int t    = blockIdx.x * 4 + wave;
    if (t >= n_nodes) return;

    const int h  = lane >> 3;
    const int r  = lane & 7;
    const int fa = h * 16 + r;          // fb = fa + 8

    const float qa = q[(size_t)t * OUT_F + fa];
    const float qb = q[(size_t)t * OUT_F + fa + 8];

    const int beg = t << 6;
    int cnt = deg[t]; if (cnt > BUCKET) cnt = BUCKET;

    // whole csr row in one coalesced load; entries >= cnt never consumed
    const int2 csrv = csr2[beg + lane];

    float acc_a = 0.f, acc_b = 0.f, den = 0.f;

    auto process = [&](unsigned long long kv, float eb) {
        unsigned int w0 = (unsigned int)kv;
        unsigned int w1 = (unsigned int)(kv >> 32);
        float ka = __uint_as_float(w0 << 16);
        float va = __uint_as_float(w0 & 0xFFFF0000u);
        float kb = __uint_as_float(w1 << 16);
        float vb = __uint_as_float(w1 & 0xFFFF0000u);
        // bit-identical tree: mul, in-lane add (= old mask-8 level), then 4,2,1
        float pa = __fmul_rn(qa, ka);
        float pb = __fmul_rn(qb, kb);
        float p  = __fadd_rn(pa, pb);
        p = __fadd_rn(p, __shfl_xor(p, 4, 8));
        p = __fadd_rn(p, __shfl_xor(p, 2, 8));
        p = __fadd_rn(p, __shfl_xor(p, 1, 8));
        float w = __expf(fmaf(p, 0.25f, eb));
        den += w;
        acc_a = fmaf(w, va, acc_a);
        acc_b = fmaf(w, vb, acc_b);
    };

    unsigned long long kv[8]; float eb[8];
    #pragma unroll
    for (int j = 0; j < 8; ++j) {
        kv[j] = 0; eb[j] = 0.f;
        if (j < cnt) {
            int src = __shfl(csrv.x, j);
            int eid = __shfl(csrv.y, j);
            kv[j] = kvpu[(size_t)src * 64 + lane];
            eb[j] = ebias[(size_t)eid * HEADS + h];
        }
    }

    int i = 0;
    while (i + 8 <= cnt) {
        unsigned long long nkv[8]; float neb[8];
        #pragma unroll
        for (int j = 0; j < 8; ++j) {
            nkv[j] = 0; neb[j] = 0.f;
            if (i + 8 + j < cnt) {
                int src = __shfl(csrv.x, i + 8 + j);
                int eid = __shfl(csrv.y, i + 8 + j);
                nkv[j] = kvpu[(size_t)src * 64 + lane];
                neb[j] = ebias[(size_t)eid * HEADS + h];
            }
        }
        #pragma unroll
        for (int j = 0; j < 8; ++j) process(kv[j], eb[j]);
        #pragma unroll
        for (int j = 0; j < 8; ++j) { kv[j] = nkv[j]; eb[j] = neb[j]; }
        i += 8;
    }
    #pragma unroll
    for (int j = 0; j < 8; ++j)
        if (i + j < cnt) process(kv[j], eb[j]);

    float d = den + 1e-10f;
    aggn[(size_t)t * OUT_F + fa]     = (unsigned short)f2bf(acc_a / d);
    aggn[(size_t)t * OUT_F + fa + 8] = (unsigned short)f2bf(acc_b / d);
}

// ---- Output projection via MFMA: aggn (bf16) @ Wo + bo ----
__global__ __launch_bounds__(256)
void out_mfma(const unsigned short* __restrict__ aggn, const bf16x8* __restrict__ WbV,
              const float* __restrict__ bo, float* __restrict__ out, int n_nodes) {
    const int tid  = threadIdx.x;
    const int wave = tid >> 6;
    const int lane = tid & 63;
    const int quad = lane >> 4;
    const int lcol = lane & 15;
    const int row0 = blockIdx.x * 64 + wave * 16;
    const int m    = row0 + lcol;

    bf16x8 afrag[4];
    const bool mv = (m < n_nodes);
    const bf16x8* ar = (const bf16x8*)(aggn + (size_t)m * OUT_F);
    #pragma unroll
    for (int kb = 0; kb < 4; ++kb) {
        if (mv) afrag[kb] = ar[kb * 4 + quad];
        else {
            bf16x8 z;
            #pragma unroll
            for (int j = 0; j < 8; ++j) z[j] = 0;
            afrag[kb] = z;
        }
    }

    #pragma unroll
    for (int ct = 0; ct < 8; ++ct) {
        f32x4 acc = {0.f, 0.f, 0.f, 0.f};
        #pragma unroll
        for (int kb = 0; kb < 4; ++kb) {
            bf16x8 b = WbV[((3 * 8 + ct) * 4 + kb) * 64 + lane];
            acc = __builtin_amdgcn_mfma_f32_16x16x32_bf16(afrag[kb], b, acc, 0, 0, 0);
        }
        const int col = ct * 16 + lcol;
        float boc = bo[col];
        #pragma unroll
        for (int r = 0; r < 4; ++r) {
            int node = row0 + quad * 4 + r;
            if (node < n_nodes) out[(size_t)node * OUT_F + col] = acc[r] + boc;
        }
    }
}

extern "C" void kernel_launch(void* const* d_in, const int* in_sizes, int n_in,
                              void* d_out, int out_size, void* d_ws, size_t ws_size,
                              hipStream_t stream) {
    const float* x  = (const float*)d_in[0];
    const int*   ei = (const int*)  d_in[1];
    const float* ef = (const float*)d_in[2];
    const float* Wq = (const float*)d_in[3];
    const float* bq = (const float*)d_in[4];
    const float* Wk = (const float*)d_in[5];
    const float* bk = (const float*)d_in[6];
    const float* Wv = (const float*)d_in[7];
    const float* bv = (const float*)d_in[8];
    const float* We = (const float*)d_in[9];
    const float* be = (const float*)d_in[10];
    const float* Wo = (const float*)d_in[11];
    const float* bo = (const float*)d_in[12];
    float* out = (float*)d_out;

    const int n_nodes = in_sizes[0] / IN_F;
    const int n_edges = in_sizes[1] / 2;

    char* w = (char*)d_ws;
    float*          q     = (float*)w;          w += (size_t)n_nodes * OUT_F * 4;
    unsigned int*   kvp   = (unsigned int*)w;   w += (size_t)n_nodes * OUT_F * 4;
    unsigned short* aggn  = (unsigned short*)w; w += (size_t)n_nodes * OUT_F * 2;
    uint4*          Wb    = (uint4*)w;          w += (size_t)8192 * 16;
    int*            deg   = (int*)w;            w += (size_t)n_nodes * 4;
    int2*           csr2  = (int2*)w;           w += (size_t)n_nodes * BUCKET * 8;
    float*          ebias = (float*)w;          // [E*8] edge-ordered bias

    // 1. weight swizzle + deg zeroing
    {
        int threads_needed = (n_nodes > 8192) ? n_nodes : 8192;
        prep_kernel<<<(threads_needed + 255) / 256, 256, 0, stream>>>(
            Wq, Wk, Wv, Wo, Wb, deg, n_nodes);
    }

    // 2. fused QKV + edge-bias + CSR scatter (16 edges/wave, 4 lanes/edge)
    {
        int node_blocks = (n_nodes + 63) / 64;
        int edge_blocks = (n_edges + 63) / 64;
        qkv_edges<<<node_blocks + edge_blocks, 256, 0, stream>>>(
            x, (const bf16x8*)Wb, bq, bk, bv, q, kvp, n_nodes,
            ef, We, be, ebias, ei, deg, csr2, n_edges, node_blocks);
    }

    // 3. aggregation (1 wave per target, 4 targets per block)
    agg_kernel<<<(n_nodes + 3) / 4, 256, 0, stream>>>(
        csr2, deg, q, (const unsigned long long*)kvp, ebias, aggn, n_nodes);

    // 4. output projection
    out_mfma<<<(n_nodes + 63) / 64, 256, 0, stream>>>(
        aggn, (const bf16x8*)Wb, bo, out, n_nodes);
}

// Round 6
// 459.076 us; speedup vs baseline: 1.3123x; 1.1309x over previous
//
#include <hip/hip_runtime.h>
#include <hip/hip_bf16.h>
#include <math.h>

#define IN_F   128
#define OUT_F  128
#define HEADS  8
#define HEAD_D 16
#define EDGE_F 64
#define BUCKET 64     // CSR bucket capacity per node

typedef __attribute__((ext_vector_type(8))) short bf16x8;
typedef __attribute__((ext_vector_type(4))) float f32x4;

// round-to-nearest-even fp32 -> bf16 bits
__device__ inline unsigned int f2bf(float f) {
    union { float f; unsigned int u; } c; c.f = f;
    unsigned int r = c.u + 0x7FFFu + ((c.u >> 16) & 1u);
    return r >> 16;
}

// kvp feature -> word permutation: word holds (k,v) packed; lane l ulong-loads
// words {2l, 2l+1} = features {h*16+r, h*16+r+8} with h=l>>3, r=l&7.
__device__ inline int wperm(int col) {
    return (col & 0x70) | ((col & 7) << 1) | ((col >> 3) & 1);
}

// ---- Prep: swizzle Wq/Wk/Wv/Wo into MFMA B-frag layout + zero deg ----
__global__ __launch_bounds__(256)
void prep_kernel(const float* __restrict__ Wq, const float* __restrict__ Wk,
                 const float* __restrict__ Wv, const float* __restrict__ Wo,
                 uint4* __restrict__ Wb, int* __restrict__ deg, int n_nodes) {
    int id = blockIdx.x * 256 + threadIdx.x;
    if (id < n_nodes) deg[id] = 0;
    if (id >= 8192) return;
    int lane = id & 63;
    int kb   = (id >> 6) & 3;
    int ct   = (id >> 8) & 7;
    int mat  = id >> 11;
    const float* W = (mat == 0) ? Wq : (mat == 1) ? Wk : (mat == 2) ? Wv : Wo;
    int n  = ct * 16 + (lane & 15);
    int k0 = kb * 32 + (lane >> 4) * 8;
    unsigned int t[8];
    #pragma unroll
    for (int j = 0; j < 8; ++j) t[j] = f2bf(W[(size_t)(k0 + j) * 128 + n]);
    uint4 val;
    val.x = t[0] | (t[1] << 16);
    val.y = t[2] | (t[3] << 16);
    val.z = t[4] | (t[5] << 16);
    val.w = t[6] | (t[7] << 16);
    Wb[id] = val;
}

// ---- Fused: QKV (node blocks) + edge-bias/scatter (edge blocks) ----
// Edge blocks: 1 wave = 16 edges; lane l = (edge l>>2, quarter l&3).
// Lane loads 16 ef floats (4 float4), 128 FMAs vs LDS We, 2-stage shfl_xor
// butterfly over the 4-lane group, edge-ordered COALESCED bias store.
__global__ __launch_bounds__(256)
void qkv_edges(const float* __restrict__ x, const bf16x8* __restrict__ WbV,
               const float* __restrict__ bq, const float* __restrict__ bk,
               const float* __restrict__ bv,
               float* __restrict__ q, unsigned int* __restrict__ kvp, int n_nodes,
               const float* __restrict__ ef, const float* __restrict__ We,
               const float* __restrict__ be, float* __restrict__ ebias,
               const int* __restrict__ ei, int* __restrict__ deg,
               int2* __restrict__ csr2, int n_edges, int node_blocks) {
    __shared__ float sWe[EDGE_F * 9];   // pad 8->9
    __shared__ float sbe[HEADS];
    const int tid = threadIdx.x;

    if ((int)blockIdx.x < node_blocks) {
        // ----------------- QKV via MFMA: 4 waves, 64 nodes/block -----------------
        const int wave = tid >> 6;
        const int lane = tid & 63;
        const int quad = lane >> 4;
        const int lcol = lane & 15;
        const int row0 = blockIdx.x * 64 + wave * 16;
        const int m    = row0 + lcol;                 // A-row this lane loads

        bf16x8 afrag[4];
        const bool mv = (m < n_nodes);
        const float* xr = x + (size_t)m * IN_F;
        #pragma unroll
        for (int kb = 0; kb < 4; ++kb) {
            float buf[8];
            if (mv) {
                float4 a = ((const float4*)(xr + kb * 32 + quad * 8))[0];
                float4 b = ((const float4*)(xr + kb * 32 + quad * 8 + 4))[0];
                buf[0]=a.x; buf[1]=a.y; buf[2]=a.z; buf[3]=a.w;
                buf[4]=b.x; buf[5]=b.y; buf[6]=b.z; buf[7]=b.w;
            } else {
                #pragma unroll
                for (int j = 0; j < 8; ++j) buf[j] = 0.f;
            }
            bf16x8 f;
            #pragma unroll
            for (int j = 0; j < 8; ++j) f[j] = (short)f2bf(buf[j]);
            afrag[kb] = f;
        }

        #pragma unroll
        for (int ct = 0; ct < 8; ++ct) {
            f32x4 aq = {0.f,0.f,0.f,0.f}, ak = {0.f,0.f,0.f,0.f}, av = {0.f,0.f,0.f,0.f};
            #pragma unroll
            for (int kb = 0; kb < 4; ++kb) {
                bf16x8 bq_ = WbV[((0 * 8 + ct) * 4 + kb) * 64 + lane];
                bf16x8 bk_ = WbV[((1 * 8 + ct) * 4 + kb) * 64 + lane];
                bf16x8 bv_ = WbV[((2 * 8 + ct) * 4 + kb) * 64 + lane];
                aq = __builtin_amdgcn_mfma_f32_16x16x32_bf16(afrag[kb], bq_, aq, 0, 0, 0);
                ak = __builtin_amdgcn_mfma_f32_16x16x32_bf16(afrag[kb], bk_, ak, 0, 0, 0);
                av = __builtin_amdgcn_mfma_f32_16x16x32_bf16(afrag[kb], bv_, av, 0, 0, 0);
            }
            const int col = ct * 16 + lcol;
            const int wcol = wperm(col);
            float bqc = bq[col], bkc = bk[col], bvc = bv[col];
            #pragma unroll
            for (int r = 0; r < 4; ++r) {
                int node = row0 + quad * 4 + r;       // C/D: row = quad*4+reg, col = lane&15
                if (node < n_nodes) {
                    q[(size_t)node * OUT_F + col]    = aq[r] + bqc;
                    kvp[(size_t)node * OUT_F + wcol] = f2bf(ak[r] + bkc) | (f2bf(av[r] + bvc) << 16);
                }
            }
        }
    } else {
        // --------- Edge bias + bucketed CSR scatter (16 edges/wave, 4 lanes/edge) ---------
        #pragma unroll
        for (int i = tid; i < EDGE_F * HEADS; i += 256)
            sWe[(i >> 3) * 9 + (i & 7)] = We[i];
        if (tid < HEADS) sbe[tid] = be[tid];
        __syncthreads();

        const int wave = tid >> 6;
        const int lane = tid & 63;
        const int g    = lane >> 2;     // edge within wave (0..15)
        const int c    = lane & 3;      // 16-float quarter of the ef row
        const int e    = (blockIdx.x - node_blocks) * 64 + wave * 16 + g;
        const bool ok  = (e < n_edges);

        // 4 float4 loads per lane; wave covers 16 full ef rows (4 KB contiguous)
        float4 a0, a1, a2, a3;
        a0 = a1 = a2 = a3 = make_float4(0.f, 0.f, 0.f, 0.f);
        if (ok) {
            const float4* er = (const float4*)(ef + (size_t)e * EDGE_F + c * 16);
            a0 = er[0]; a1 = er[1]; a2 = er[2]; a3 = er[3];
        }

        // one lane per edge: indices + atomic + csr store (hidden under FMA tree)
        if (ok && c == 0) {
            int s_ = ei[e];
            int t_ = ei[n_edges + e];
            int pos = atomicAdd(&deg[t_], 1);
            if (pos < BUCKET) csr2[((size_t)t_ << 6) + pos] = make_int2(s_, e);
        }

        // partial MLP: 16 ef values x 8 heads
        float acc[HEADS];
        #pragma unroll
        for (int h = 0; h < HEADS; ++h) acc[h] = 0.f;
        float evv[16] = {a0.x, a0.y, a0.z, a0.w, a1.x, a1.y, a1.z, a1.w,
                         a2.x, a2.y, a2.z, a2.w, a3.x, a3.y, a3.z, a3.w};
        #pragma unroll
        for (int jj = 0; jj < 16; ++jj) {
            #pragma unroll
            for (int h = 0; h < HEADS; ++h)
                acc[h] = fmaf(evv[jj], sWe[(c * 16 + jj) * 9 + h], acc[h]);
        }
        // butterfly over the 4-lane group
        #pragma unroll
        for (int m = 1; m < 4; m <<= 1) {
            #pragma unroll
            for (int h = 0; h < HEADS; ++h)
                acc[h] += __shfl_xor(acc[h], m, 4);
        }
        // edge-ordered coalesced store: lane c writes heads {2c, 2c+1}
        if (ok) {
            float2 st = make_float2(acc[2 * c]     + sbe[2 * c],
                                    acc[2 * c + 1] + sbe[2 * c + 1]);
            ((float2*)(ebias + (size_t)e * HEADS))[c] = st;
        }
    }
}

// ---- Aggregation: 1 wave per target, 4 targets/block ----
// Per wave: stage csr row as PRECOMPUTED byte offsets (src*512, eid*32) in a
// wave-private LDS table. Per slot: one broadcast ds_read_b64 -> 32-bit voffset
// loads (SGPR base). Dead slots (cnt rounded up to 4) use clamped offsets and
// eb=-1e30 -> exp()==0.0 exactly -> exact zero contribution, no branches.
// 3-batch pipeline: load batch i+8 while processing batch i.
// lane l owns features fa=(l>>3)*16+(l&7), fb=fa+8 via one ulong kvp load.
__global__ __launch_bounds__(256)
void agg_kernel(const int2* __restrict__ csr2, const int* __restrict__ deg,
                const float* __restrict__ q, const char* __restrict__ kvpb,
                const char* __restrict__ ebiasb, unsigned short* __restrict__ aggn,
                int n_nodes) {
    __shared__ int2 soff[4][BUCKET];
    const int tid  = threadIdx.x;
    const int wave = tid >> 6;
    const int lane = tid & 63;
    const int t    = blockIdx.x * 4 + wave;

    const int h  = lane >> 3;
    const int r  = lane & 7;
    const int fa = h * 16 + r;          // fb = fa + 8
    const int kvo_lane = lane << 3;     // +lane*8 bytes into the kv row
    const int ebo_lane = h << 2;        // +h*4 bytes into the ebias row

    int cnt = 0;
    if (t < n_nodes) {
        cnt = deg[t]; if (cnt > BUCKET) cnt = BUCKET;
        int2 se = csr2[((size_t)t << 6) + lane];   // coalesced row load (always in-bounds)
        if (lane >= cnt) se = make_int2(0, 0);     // clamp dead entries (poison-safe)
        soff[wave][lane] = make_int2(se.x << 9, se.y << 5);  // src*512B, eid*32B
    }
    __syncthreads();            // orders the wave-private ds_write before ds_read
    if (t >= n_nodes) return;

    const float qa = q[(size_t)t * OUT_F + fa];
    const float qb = q[(size_t)t * OUT_F + fa + 8];

    const int cntR = (cnt + 3) & ~3;

    float acc_a = 0.f, acc_b = 0.f, den = 0.f;

    auto process = [&](unsigned long long kv, float eb) {
        unsigned int w0 = (unsigned int)kv;
        unsigned int w1 = (unsigned int)(kv >> 32);
        float ka = __uint_as_float(w0 << 16);
        float va = __uint_as_float(w0 & 0xFFFF0000u);
        float kb = __uint_as_float(w1 << 16);
        float vb = __uint_as_float(w1 & 0xFFFF0000u);
        // bit-identical tree: mul, in-lane add (= old mask-8 level), then 4,2,1
        float pa = __fmul_rn(qa, ka);
        float pb = __fmul_rn(qb, kb);
        float p  = __fadd_rn(pa, pb);
        p = __fadd_rn(p, __shfl_xor(p, 4, 8));
        p = __fadd_rn(p, __shfl_xor(p, 2, 8));
        p = __fadd_rn(p, __shfl_xor(p, 1, 8));
        float w = __expf(fmaf(p, 0.25f, eb));      // dead slots: exp(-1e30) == 0.0f
        den += w;
        acc_a = fmaf(w, va, acc_a);
        acc_b = fmaf(w, vb, acc_b);
    };

    auto load4 = [&](int base, unsigned long long* kvd, float* ebd) {
        #pragma unroll
        for (int jj = 0; jj < 4; ++jj) {
            int slot = base + jj;                   // wave-uniform
            int2 off = soff[wave][slot];            // broadcast ds_read_b64
            unsigned long long kvv =
                *(const unsigned long long*)(kvpb + (size_t)(unsigned)(off.x + kvo_lane));
            float e_ =
                *(const float*)(ebiasb + (size_t)(unsigned)(off.y + ebo_lane));
            kvd[jj] = kvv;
            ebd[jj] = (slot < cnt) ? e_ : -1e30f;   // kill dead slots exactly
        }
    };

    unsigned long long kvA[4], kvB[4];
    float ebA[4], ebB[4];
    if (cntR > 0) load4(0, kvA, ebA);
    if (cntR > 4) load4(4, kvB, ebB);

    int i = 0;
    while (i + 8 < cntR) {
        unsigned long long nk[4]; float ne[4];
        load4(i + 8, nk, ne);
        #pragma unroll
        for (int jj = 0; jj < 4; ++jj) process(kvA[jj], ebA[jj]);
        #pragma unroll
        for (int jj = 0; jj < 4; ++jj) { kvA[jj] = kvB[jj]; ebA[jj] = ebB[jj]; }
        #pragma unroll
        for (int jj = 0; jj < 4; ++jj) { kvB[jj] = nk[jj]; ebB[jj] = ne[jj]; }
        i += 4;
    }
    if (cntR > 0) {
        #pragma unroll
        for (int jj = 0; jj < 4; ++jj) process(kvA[jj], ebA[jj]);
    }
    if (cntR > 4) {
        #pragma unroll
        for (int jj = 0; jj < 4; ++jj) process(kvB[jj], ebB[jj]);
    }

    float d = den + 1e-10f;
    aggn[(size_t)t * OUT_F + fa]     = (unsigned short)f2bf(acc_a / d);
    aggn[(size_t)t * OUT_F + fa + 8] = (unsigned short)f2bf(acc_b / d);
}

// ---- Output projection via MFMA: aggn (bf16) @ Wo + bo ----
__global__ __launch_bounds__(256)
void out_mfma(const unsigned short* __restrict__ aggn, const bf16x8* __restrict__ WbV,
              const float* __restrict__ bo, float* __restrict__ out, int n_nodes) {
    const int tid  = threadIdx.x;
    const int wave = tid >> 6;
    const int lane = tid & 63;
    const int quad = lane >> 4;
    const int lcol = lane & 15;
    const int row0 = blockIdx.x * 64 + wave * 16;
    const int m    = row0 + lcol;

    bf16x8 afrag[4];
    const bool mv = (m < n_nodes);
    const bf16x8* ar = (const bf16x8*)(aggn + (size_t)m * OUT_F);
    #pragma unroll
    for (int kb = 0; kb < 4; ++kb) {
        if (mv) afrag[kb] = ar[kb * 4 + quad];
        else {
            bf16x8 z;
            #pragma unroll
            for (int j = 0; j < 8; ++j) z[j] = 0;
            afrag[kb] = z;
        }
    }

    #pragma unroll
    for (int ct = 0; ct < 8; ++ct) {
        f32x4 acc = {0.f, 0.f, 0.f, 0.f};
        #pragma unroll
        for (int kb = 0; kb < 4; ++kb) {
            bf16x8 b = WbV[((3 * 8 + ct) * 4 + kb) * 64 + lane];
            acc = __builtin_amdgcn_mfma_f32_16x16x32_bf16(afrag[kb], b, acc, 0, 0, 0);
        }
        const int col = ct * 16 + lcol;
        float boc = bo[col];
        #pragma unroll
        for (int r = 0; r < 4; ++r) {
            int node = row0 + quad * 4 + r;
            if (node < n_nodes) out[(size_t)node * OUT_F + col] = acc[r] + boc;
        }
    }
}

extern "C" void kernel_launch(void* const* d_in, const int* in_sizes, int n_in,
                              void* d_out, int out_size, void* d_ws, size_t ws_size,
                              hipStream_t stream) {
    const float* x  = (const float*)d_in[0];
    const int*   ei = (const int*)  d_in[1];
    const float* ef = (const float*)d_in[2];
    const float* Wq = (const float*)d_in[3];
    const float* bq = (const float*)d_in[4];
    const float* Wk = (const float*)d_in[5];
    const float* bk = (const float*)d_in[6];
    const float* Wv = (const float*)d_in[7];
    const float* bv = (const float*)d_in[8];
    const float* We = (const float*)d_in[9];
    const float* be = (const float*)d_in[10];
    const float* Wo = (const float*)d_in[11];
    const float* bo = (const float*)d_in[12];
    float* out = (float*)d_out;

    const int n_nodes = in_sizes[0] / IN_F;
    const int n_edges = in_sizes[1] / 2;

    char* w = (char*)d_ws;
    float*          q     = (float*)w;          w += (size_t)n_nodes * OUT_F * 4;
    unsigned int*   kvp   = (unsigned int*)w;   w += (size_t)n_nodes * OUT_F * 4;
    unsigned short* aggn  = (unsigned short*)w; w += (size_t)n_nodes * OUT_F * 2;
    uint4*          Wb    = (uint4*)w;          w += (size_t)8192 * 16;
    int*            deg   = (int*)w;            w += (size_t)n_nodes * 4;
    int2*           csr2  = (int2*)w;           w += (size_t)n_nodes * BUCKET * 8;
    float*          ebias = (float*)w;          // [E*8] edge-ordered bias

    // 1. weight swizzle + deg zeroing
    {
        int threads_needed = (n_nodes > 8192) ? n_nodes : 8192;
        prep_kernel<<<(threads_needed + 255) / 256, 256, 0, stream>>>(
            Wq, Wk, Wv, Wo, Wb, deg, n_nodes);
    }

    // 2. fused QKV + edge-bias + CSR scatter (16 edges/wave, 4 lanes/edge)
    {
        int node_blocks = (n_nodes + 63) / 64;
        int edge_blocks = (n_edges + 63) / 64;
        qkv_edges<<<node_blocks + edge_blocks, 256, 0, stream>>>(
            x, (const bf16x8*)Wb, bq, bk, bv, q, kvp, n_nodes,
            ef, We, be, ebias, ei, deg, csr2, n_edges, node_blocks);
    }

    // 3. aggregation (1 wave per target, 4 targets per block)
    agg_kernel<<<(n_nodes + 3) / 4, 256, 0, stream>>>(
        csr2, deg, q, (const char*)kvp, (const char*)ebias, aggn, n_nodes);

    // 4. output projection
    out_mfma<<<(n_nodes + 63) / 64, 256, 0, stream>>>(
        aggn, (const bf16x8*)Wb, bo, out, n_nodes);
}